// Round 2
// baseline (802.273 us; speedup 1.0000x reference)
//
#include <hip/hip_runtime.h>

// RoIHeads pipeline: roi_align -> FC1(relu) -> FC2(relu) -> cls/box heads ->
// softmax/decode/clip/mask -> per-class NMS. All fp32 (no fp32 MFMA on CDNA4;
// bf16 path deferred until validation tolerance is known).
//
// R2 changes vs R1 baseline (no bench feedback yet — theory-driven):
//  - pooled layout p-major: pooled[n][p*256+c] -> coalesced roi_align stores;
//    GEMM1 permutes w1 row index (k'=p*256+c -> row c*49+p) to compensate.
//  - GEMM: BM=64 BN=128 BK=32, 4x8 micro-tile, split-K=4 (partials + reduce)
//    -> 512 blocks (2/CU), half the barriers, better FMA:LDS issue ratio.

#define NEGV -1000000000.0f

// ---------------- RoI align ----------------
// grid = (49, 1000), block = 256 (one thread/channel); pooled[n][p*256+c]
__global__ __launch_bounds__(256) void roi_align_k(const float* __restrict__ feat,
    const float* __restrict__ prop, float* __restrict__ pooled)
{
    int n = blockIdx.y;
    int p = blockIdx.x;            // 0..48
    int my = p / 7, mx = p % 7;
    float x1 = prop[n * 4 + 0] * 0.0625f;
    float y1 = prop[n * 4 + 1] * 0.0625f;
    float x2 = prop[n * 4 + 2] * 0.0625f;
    float y2 = prop[n * 4 + 3] * 0.0625f;
    float rw = fmaxf(x2 - x1, 1.0f), rh = fmaxf(y2 - y1, 1.0f);
    float y = y1 + ((float)my + 0.5f) * (rh / 7.0f);
    float x = x1 + ((float)mx + 0.5f) * (rw / 7.0f);
    bool oob = (y < -1.0f) || (y > 50.0f) || (x < -1.0f) || (x > 50.0f);
    y = fminf(fmaxf(y, 0.0f), 49.0f);
    x = fminf(fmaxf(x, 0.0f), 49.0f);
    int y0 = (int)floorf(y), x0 = (int)floorf(x);
    int y1i = min(y0 + 1, 49), x1i = min(x0 + 1, 49);
    float ly = y - (float)y0, lx = x - (float)x0;
    float hy = 1.0f - ly, hx = 1.0f - lx;
    float w00 = hy * hx, w01 = hy * lx, w10 = ly * hx, w11 = ly * lx;
    int c = threadIdx.x;
    float v = feat[(y0 * 50 + x0) * 256 + c] * w00
            + feat[(y0 * 50 + x1i) * 256 + c] * w01
            + feat[(y1i * 50 + x0) * 256 + c] * w10
            + feat[(y1i * 50 + x1i) * 256 + c] * w11;
    if (oob) v = 0.0f;
    pooled[(size_t)n * 12544 + p * 256 + c] = v;   // coalesced
}

// ---------------- fp32 split-K GEMM (partials, no bias) ----------------
// part[s][M][N] = A[M, s*Ks:(s+1)*Ks] @ B[.,N].  BM=64 BN=128 BK=32,
// 256 thr, 4x8 micro-tile. grid = (N/128, ceil(M/64), S).
// permute!=0: B row index k' (p-major, k'=p*256+c) -> physical row c*49+p.
__global__ __launch_bounds__(256, 2) void gemm_splitk(const float* __restrict__ A,
    const float* __restrict__ B, float* __restrict__ part,
    int Mdim, int Ndim, int Kdim, int Ks, int permute)
{
    __shared__ float As[32][68];    // [k][m], pad 68: b128-aligned reads, <=4-way stage writes
    __shared__ float Bs[32][128];   // [k][n]
    int tid = threadIdx.x;
    int col0 = blockIdx.x * 128;
    int row0 = blockIdx.y * 64;
    int kOff = blockIdx.z * Ks;
    int ty = tid >> 4, tx = tid & 15;   // rows ty*4+i, cols tx*8+j
    float acc[4][8] = {};
    for (int k0 = 0; k0 < Ks; k0 += 32) {
        // stage A: 64 rows x 32 k, transposed into As[k][r]
#pragma unroll
        for (int i = 0; i < 2; ++i) {
            int idx = tid + i * 256;        // 0..511
            int r = idx >> 3, f = idx & 7;  // r 0..63, f 0..7
            int gr = row0 + r;
            float4 av = make_float4(0.f, 0.f, 0.f, 0.f);
            if (gr < Mdim)
                av = *(const float4*)&A[(size_t)gr * Kdim + kOff + k0 + f * 4];
            As[f * 4 + 0][r] = av.x;
            As[f * 4 + 1][r] = av.y;
            As[f * 4 + 2][r] = av.z;
            As[f * 4 + 3][r] = av.w;
        }
        // stage B: 32 k x 128 cols (f4 coalesced)
#pragma unroll
        for (int i = 0; i < 4; ++i) {
            int idx = tid + i * 256;            // 0..1023
            int kr = idx >> 5, f = idx & 31;    // kr 0..31, f 0..31
            int kg = kOff + k0 + kr;
            int brv = permute ? ((kg & 255) * 49 + (kg >> 8)) : kg;
            *(float4*)&Bs[kr][f * 4] = *(const float4*)&B[(size_t)brv * Ndim + col0 + f * 4];
        }
        __syncthreads();
#pragma unroll 8
        for (int kk = 0; kk < 32; ++kk) {
            float4 a  = *(const float4*)&As[kk][ty * 4];
            float4 b0 = *(const float4*)&Bs[kk][tx * 8];
            float4 b1 = *(const float4*)&Bs[kk][tx * 8 + 4];
            float ar[4] = {a.x, a.y, a.z, a.w};
            float br8[8] = {b0.x, b0.y, b0.z, b0.w, b1.x, b1.y, b1.z, b1.w};
#pragma unroll
            for (int i2 = 0; i2 < 4; ++i2)
#pragma unroll
                for (int j = 0; j < 8; ++j)
                    acc[i2][j] += ar[i2] * br8[j];
        }
        __syncthreads();
    }
    float* dst = part + (size_t)blockIdx.z * Mdim * Ndim;
    int gc = col0 + tx * 8;
#pragma unroll
    for (int i2 = 0; i2 < 4; ++i2) {
        int gr = row0 + ty * 4 + i2;
        if (gr < Mdim) {
            *(float4*)&dst[(size_t)gr * Ndim + gc] =
                make_float4(acc[i2][0], acc[i2][1], acc[i2][2], acc[i2][3]);
            *(float4*)&dst[(size_t)gr * Ndim + gc + 4] =
                make_float4(acc[i2][4], acc[i2][5], acc[i2][6], acc[i2][7]);
        }
    }
}

// ---------------- split-K reduce + bias + relu ----------------
// grid = M blocks, 256 thr (N=1024 as f4). Deterministic order.
__global__ __launch_bounds__(256) void reduce_bias_relu_k(const float* __restrict__ part,
    const float* __restrict__ bias, float* __restrict__ outp, int Ndim, int S, int MN)
{
    int m = blockIdx.x, t = threadIdx.x;
    size_t o = (size_t)m * Ndim + t * 4;
    float4 acc = *(const float4*)&part[o];
    for (int s = 1; s < S; ++s) {
        float4 p = *(const float4*)&part[(size_t)s * MN + o];
        acc.x += p.x; acc.y += p.y; acc.z += p.z; acc.w += p.w;
    }
    float4 bv = *(const float4*)&bias[t * 4];
    acc.x = fmaxf(acc.x + bv.x, 0.f);
    acc.y = fmaxf(acc.y + bv.y, 0.f);
    acc.z = fmaxf(acc.z + bv.z, 0.f);
    acc.w = fmaxf(acc.w + bv.w, 0.f);
    *(float4*)&outp[o] = acc;
}

// ---------------- cls/box heads ----------------
// grid = 1000 blocks, 128 thr: thr 0..20 -> logits col, 21..104 -> box col
__global__ __launch_bounds__(128) void heads_k(const float* __restrict__ h,
    const float* __restrict__ w_cls, const float* __restrict__ b_cls,
    const float* __restrict__ w_box, const float* __restrict__ b_box,
    float* __restrict__ logits, float* __restrict__ deltas)
{
    __shared__ float sh[1024];
    int n = blockIdx.x;
    for (int i = threadIdx.x; i < 1024; i += 128) sh[i] = h[(size_t)n * 1024 + i];
    __syncthreads();
    int j = threadIdx.x;
    if (j < 21) {
        float acc = b_cls[j];
        for (int k = 0; k < 1024; ++k) acc += sh[k] * w_cls[k * 21 + j];
        logits[n * 21 + j] = acc;
    } else if (j < 105) {
        int jj = j - 21;
        float acc = b_box[jj];
        for (int k = 0; k < 1024; ++k) acc += sh[k] * w_box[k * 84 + jj];
        deltas[n * 84 + jj] = acc;
    }
}

// ---------------- softmax + decode + clip + mask ----------------
__global__ __launch_bounds__(64) void postproc_k(const float* __restrict__ logits,
    const float* __restrict__ deltas, const float* __restrict__ prop,
    const int* __restrict__ img_h_p, const int* __restrict__ img_w_p,
    float* __restrict__ scores_m, float* __restrict__ boxes_dec)
{
    int n = blockIdx.x;
    int cls = threadIdx.x;
    if (cls < 1 || cls > 20) return;
    float mx = -3.0e38f;
    for (int i = 0; i < 21; ++i) mx = fmaxf(mx, logits[n * 21 + i]);
    float sum = 0.f;
    for (int i = 0; i < 21; ++i) sum += expf(logits[n * 21 + i] - mx);
    float score = expf(logits[n * 21 + cls] - mx) / sum;

    float p0 = prop[n * 4 + 0], p1 = prop[n * 4 + 1];
    float p2 = prop[n * 4 + 2], p3 = prop[n * 4 + 3];
    float w = p2 - p0, h = p3 - p1;
    float cx = p0 + 0.5f * w, cy = p1 + 0.5f * h;
    float d0 = deltas[n * 84 + cls * 4 + 0];
    float d1 = deltas[n * 84 + cls * 4 + 1];
    float d2 = deltas[n * 84 + cls * 4 + 2];
    float d3 = deltas[n * 84 + cls * 4 + 3];
    const float CLIP = 4.135166556742356f;  // log(1000/16)
    float dx = d0 / 10.0f, dy = d1 / 10.0f;
    float dw = fminf(d2 / 5.0f, CLIP), dh = fminf(d3 / 5.0f, CLIP);
    float pcx = dx * w + cx, pcy = dy * h + cy;
    float pw = expf(dw) * w, ph = expf(dh) * h;
    float bx1 = pcx - 0.5f * pw, by1 = pcy - 0.5f * ph;
    float bx2 = pcx + 0.5f * pw, by2 = pcy + 0.5f * ph;
    float iw = (float)img_w_p[0], ih = (float)img_h_p[0];
    bx1 = fminf(fmaxf(bx1, 0.f), iw);
    by1 = fminf(fmaxf(by1, 0.f), ih);
    bx2 = fminf(fmaxf(bx2, 0.f), iw);
    by2 = fminf(fmaxf(by2, 0.f), ih);
    float bw = bx2 - bx1, bh = by2 - by1;
    bool keep = (bw >= 1.0f) && (bh >= 1.0f) && (score >= 0.05f);
    int o = (cls - 1) * 1000 + n;
    scores_m[o] = keep ? score : NEGV;
    ((float4*)boxes_dec)[o] = make_float4(bx1, by1, bx2, by2);
}

// ---------------- per-class NMS ----------------
// grid = 20 blocks (one/class), 1024 thr. Exact JAX scan semantics:
// argmax (first-index tiebreak), suppress IoU>0.5, s[i]=NEG, 100 slots.
// Early exit when max==NEG is semantics-preserving (remaining slots -> 0).
__global__ __launch_bounds__(1024) void nms_k(const float* __restrict__ scores_m,
    const float* __restrict__ boxes_dec, float* __restrict__ out)
{
    int cls = blockIdx.x;
    int t = threadIdx.x;
    __shared__ float s[1000];
    __shared__ float4 bx[1000];
    __shared__ unsigned long long red[16];
    __shared__ float4 selb_s;
    __shared__ int seli_s;
    __shared__ int done_s;
    if (t < 1000) {
        s[t] = scores_m[cls * 1000 + t];
        bx[t] = ((const float4*)boxes_dec)[cls * 1000 + t];
    }
    float* kb  = out;            // [2000][4]
    float* ksc = out + 8000;     // [2000]
    float* klab = out + 10000;   // [2000]
    if (t < 100) klab[cls * 100 + t] = (float)(cls + 1);
    if (t == 0) done_s = 0;
    __syncthreads();
    for (int it = 0; it < 100; ++it) {
        float v = (t < 1000) ? s[t] : -3.0e38f;
        unsigned ub = __float_as_uint(v);
        ub = (ub & 0x80000000u) ? ~ub : (ub | 0x80000000u);
        unsigned long long key = ((unsigned long long)ub << 32) | (unsigned)(1023 - t);
#pragma unroll
        for (int off = 1; off < 64; off <<= 1) {
            unsigned long long o = __shfl_xor(key, off, 64);
            key = (o > key) ? o : key;
        }
        if ((t & 63) == 0) red[t >> 6] = key;
        __syncthreads();
        if (t == 0) {
            unsigned long long best = red[0];
            for (int i = 1; i < 16; ++i) if (red[i] > best) best = red[i];
            int idx = 1023 - (int)(best & 0xFFFFFFFFu);
            float bv = s[idx];
            seli_s = idx;
            selb_s = bx[idx];
            if (bv <= 0.5f * NEGV) {
                done_s = 1;
            } else {
                ((float4*)kb)[cls * 100 + it] = bx[idx];
                ksc[cls * 100 + it] = bv;
            }
        }
        __syncthreads();
        if (done_s) {
            for (int k = it + t; k < 100; k += 1024) {
                ((float4*)kb)[cls * 100 + k] = make_float4(0.f, 0.f, 0.f, 0.f);
                ksc[cls * 100 + k] = 0.0f;
            }
            break;
        }
        if (t < 1000) {
            float4 b = selb_s;
            float4 c = bx[t];
            float ltx = fmaxf(b.x, c.x), lty = fmaxf(b.y, c.y);
            float rbx = fminf(b.z, c.z), rby = fminf(b.w, c.w);
            float wiw = fmaxf(rbx - ltx, 0.0f), wih = fmaxf(rby - lty, 0.0f);
            float inter = wiw * wih;
            float a1 = (b.z - b.x) * (b.w - b.y);
            float a2 = (c.z - c.x) * (c.w - c.y);
            float iou = inter / (a1 + a2 - inter + 1e-9f);
            if (iou > 0.5f || t == seli_s) s[t] = NEGV;
        }
        __syncthreads();
    }
}

extern "C" void kernel_launch(void* const* d_in, const int* in_sizes, int n_in,
                              void* d_out, int out_size, void* d_ws, size_t ws_size,
                              hipStream_t stream)
{
    const float* feat  = (const float*)d_in[0];
    const float* prop  = (const float*)d_in[1];
    const float* w1    = (const float*)d_in[2];
    const float* b1    = (const float*)d_in[3];
    const float* w2    = (const float*)d_in[4];
    const float* b2    = (const float*)d_in[5];
    const float* w_cls = (const float*)d_in[6];
    const float* b_cls = (const float*)d_in[7];
    const float* w_box = (const float*)d_in[8];
    const float* b_box = (const float*)d_in[9];
    const int* img_h   = (const int*)d_in[10];
    const int* img_w   = (const int*)d_in[11];

    float* ws = (float*)d_ws;
    float* pooled    = ws;                       // 1000*12544        (p-major K)
    float* h1        = pooled + 12544000;        // 1000*1024
    float* h2        = h1 + 1024000;             // 1000*1024
    float* part      = h2 + 1024000;             // 4*1000*1024 (shared GEMM1/GEMM2)
    float* logits    = part + 4096000;           // 1000*21
    float* deltas    = logits + 21000;           // 1000*84
    float* scores_m  = deltas + 84000;           // 20*1000
    float* boxes_dec = scores_m + 20000;         // 20*1000*4
    float* outp = (float*)d_out;                 // kb 8000 | ksc 2000 | labels 2000

    hipLaunchKernelGGL(roi_align_k, dim3(49, 1000), dim3(256), 0, stream, feat, prop, pooled);
    // GEMM1: pooled[1000,12544] @ w1 -> part (split-K 4, permuted w1 rows)
    hipLaunchKernelGGL(gemm_splitk, dim3(8, 16, 4), dim3(256), 0, stream,
                       pooled, w1, part, 1000, 1024, 12544, 3136, 1);
    hipLaunchKernelGGL(reduce_bias_relu_k, dim3(1000), dim3(256), 0, stream,
                       part, b1, h1, 1024, 4, 1024000);
    // GEMM2: h1[1000,1024] @ w2 -> part (split-K 4)
    hipLaunchKernelGGL(gemm_splitk, dim3(8, 16, 4), dim3(256), 0, stream,
                       h1, w2, part, 1000, 1024, 1024, 256, 0);
    hipLaunchKernelGGL(reduce_bias_relu_k, dim3(1000), dim3(256), 0, stream,
                       part, b2, h2, 1024, 4, 1024000);
    hipLaunchKernelGGL(heads_k, dim3(1000), dim3(128), 0, stream,
                       h2, w_cls, b_cls, w_box, b_box, logits, deltas);
    hipLaunchKernelGGL(postproc_k, dim3(1000), dim3(64), 0, stream,
                       logits, deltas, prop, img_h, img_w, scores_m, boxes_dec);
    hipLaunchKernelGGL(nms_k, dim3(20), dim3(1024), 0, stream, scores_m, boxes_dec, outp);
}

// Round 3
// 778.905 us; speedup vs baseline: 1.0300x; 1.0300x over previous
//
#include <hip/hip_runtime.h>

// RoIHeads pipeline: roi_align -> FC1(relu) -> FC2(relu) -> cls/box heads ->
// softmax/decode/clip/mask -> per-class NMS. All fp32 (no fp32 MFMA on CDNA4).
//
// R3 changes (from R2 rocprof: GEMM1 474us, VALUBusy 46%, LDS_BANK_CONFLICT 6.1e7):
//  - B-frag read mapping tx*4 / 64+tx*4 (contiguous 256B sweeps, 2-way = free)
//    instead of tx*8 (4-way on half the banks).
//  - A-staging XOR swizzle (col = r ^ ((f&3)<<3)): write conflicts 4-way -> 2-way.
//  - Register prefetch: next tile's global loads issued BEFORE compute phase,
//    reg->LDS store at loop top -> no exposed global latency at barriers.

#define NEGV -1000000000.0f

// ---------------- RoI align ----------------
// grid = (49, 1000), block = 256 (one thread/channel); pooled[n][p*256+c]
__global__ __launch_bounds__(256) void roi_align_k(const float* __restrict__ feat,
    const float* __restrict__ prop, float* __restrict__ pooled)
{
    int n = blockIdx.y;
    int p = blockIdx.x;            // 0..48
    int my = p / 7, mx = p % 7;
    float x1 = prop[n * 4 + 0] * 0.0625f;
    float y1 = prop[n * 4 + 1] * 0.0625f;
    float x2 = prop[n * 4 + 2] * 0.0625f;
    float y2 = prop[n * 4 + 3] * 0.0625f;
    float rw = fmaxf(x2 - x1, 1.0f), rh = fmaxf(y2 - y1, 1.0f);
    float y = y1 + ((float)my + 0.5f) * (rh / 7.0f);
    float x = x1 + ((float)mx + 0.5f) * (rw / 7.0f);
    bool oob = (y < -1.0f) || (y > 50.0f) || (x < -1.0f) || (x > 50.0f);
    y = fminf(fmaxf(y, 0.0f), 49.0f);
    x = fminf(fmaxf(x, 0.0f), 49.0f);
    int y0 = (int)floorf(y), x0 = (int)floorf(x);
    int y1i = min(y0 + 1, 49), x1i = min(x0 + 1, 49);
    float ly = y - (float)y0, lx = x - (float)x0;
    float hy = 1.0f - ly, hx = 1.0f - lx;
    float w00 = hy * hx, w01 = hy * lx, w10 = ly * hx, w11 = ly * lx;
    int c = threadIdx.x;
    float v = feat[(y0 * 50 + x0) * 256 + c] * w00
            + feat[(y0 * 50 + x1i) * 256 + c] * w01
            + feat[(y1i * 50 + x0) * 256 + c] * w10
            + feat[(y1i * 50 + x1i) * 256 + c] * w11;
    if (oob) v = 0.0f;
    pooled[(size_t)n * 12544 + p * 256 + c] = v;   // coalesced
}

// ---------------- fp32 split-K GEMM (partials, no bias) ----------------
// part[s][M][N] = A[M, s*Ks..] @ B[.,N].  BM=64 BN=128 BK=32, 256 thr,
// 4x8 micro-tile (cols tx*4..+3 and 64+tx*4..+3). grid = (N/128, ceil(M/64), S).
// permute!=0: B row k' (p-major, k'=p*256+c) -> physical row c*49+p.
__global__ __launch_bounds__(256) void gemm_splitk(const float* __restrict__ A,
    const float* __restrict__ B, float* __restrict__ part,
    int Mdim, int Ndim, int Kdim, int Ks, int permute)
{
    __shared__ float As[32][68];    // [k][r ^ ((f&3)<<3)] swizzled, 2-way writes
    __shared__ float Bs[32][128];   // [k][n] linear
    int tid = threadIdx.x;
    int col0 = blockIdx.x * 128;
    int row0 = blockIdx.y * 64;
    int kOff = blockIdx.z * Ks;
    int ty = tid >> 4, tx = tid & 15;

    // A staging: idx = tid + 256*i -> r = idx>>3 (0..63), f = idx&7 (k-group)
    int ar0 = tid >> 3;            // 0..31 (i=0), +32 for i=1
    int af  = tid & 7;
    int aswz = (af & 3) << 3;
    // B staging: idx = tid + 256*i -> kr = idx>>5 (0..31), f = idx&31
    int bkr0 = tid >> 5;           // 0..7, +8*i
    int bf   = tid & 31;

    float4 pa0, pa1, pb0, pb1, pb2, pb3;

    auto loadA = [&](int k0) {
        int gr0 = row0 + ar0;
        int gr1 = gr0 + 32;
        pa0 = make_float4(0.f, 0.f, 0.f, 0.f);
        pa1 = make_float4(0.f, 0.f, 0.f, 0.f);
        if (gr0 < Mdim) pa0 = *(const float4*)&A[(size_t)gr0 * Kdim + kOff + k0 + af * 4];
        if (gr1 < Mdim) pa1 = *(const float4*)&A[(size_t)gr1 * Kdim + kOff + k0 + af * 4];
    };
    auto rowB = [&](int k0, int i) {
        int kg = kOff + k0 + bkr0 + 8 * i;
        int brv = permute ? ((kg & 255) * 49 + (kg >> 8)) : kg;
        return (const float4*)&B[(size_t)brv * Ndim + col0 + bf * 4];
    };
    auto loadB = [&](int k0) {
        pb0 = *rowB(k0, 0);
        pb1 = *rowB(k0, 1);
        pb2 = *rowB(k0, 2);
        pb3 = *rowB(k0, 3);
    };
    auto store = [&]() {
        int rc0 = ar0 ^ aswz;
        int rc1 = (ar0 + 32) ^ aswz;
        As[af * 4 + 0][rc0] = pa0.x;
        As[af * 4 + 1][rc0] = pa0.y;
        As[af * 4 + 2][rc0] = pa0.z;
        As[af * 4 + 3][rc0] = pa0.w;
        As[af * 4 + 0][rc1] = pa1.x;
        As[af * 4 + 1][rc1] = pa1.y;
        As[af * 4 + 2][rc1] = pa1.z;
        As[af * 4 + 3][rc1] = pa1.w;
        *(float4*)&Bs[bkr0 +  0][bf * 4] = pb0;
        *(float4*)&Bs[bkr0 +  8][bf * 4] = pb1;
        *(float4*)&Bs[bkr0 + 16][bf * 4] = pb2;
        *(float4*)&Bs[bkr0 + 24][bf * 4] = pb3;
    };

    float acc[4][8] = {};
    loadA(0); loadB(0);
    for (int k0 = 0; k0 < Ks; k0 += 32) {
        __syncthreads();            // all waves done reading previous tile
        store();                    // (compiler waits the prefetched loads here)
        __syncthreads();            // tile ready
        if (k0 + 32 < Ks) { loadA(k0 + 32); loadB(k0 + 32); }  // overlap w/ compute
#pragma unroll 8
        for (int kk = 0; kk < 32; ++kk) {
            int sa = ((kk >> 2) & 3) << 3;
            float4 a  = *(const float4*)&As[kk][(ty * 4) ^ sa];
            float4 b0 = *(const float4*)&Bs[kk][tx * 4];        // 2-way, free
            float4 b1 = *(const float4*)&Bs[kk][64 + tx * 4];   // 2-way, free
            float ar[4] = {a.x, a.y, a.z, a.w};
            float br[8] = {b0.x, b0.y, b0.z, b0.w, b1.x, b1.y, b1.z, b1.w};
#pragma unroll
            for (int i2 = 0; i2 < 4; ++i2)
#pragma unroll
                for (int j = 0; j < 8; ++j)
                    acc[i2][j] += ar[i2] * br[j];
        }
    }
    float* dst = part + (size_t)blockIdx.z * Mdim * Ndim;
    int gcA = col0 + tx * 4, gcB = col0 + 64 + tx * 4;
#pragma unroll
    for (int i2 = 0; i2 < 4; ++i2) {
        int gr = row0 + ty * 4 + i2;
        if (gr < Mdim) {
            *(float4*)&dst[(size_t)gr * Ndim + gcA] =
                make_float4(acc[i2][0], acc[i2][1], acc[i2][2], acc[i2][3]);
            *(float4*)&dst[(size_t)gr * Ndim + gcB] =
                make_float4(acc[i2][4], acc[i2][5], acc[i2][6], acc[i2][7]);
        }
    }
}

// ---------------- split-K reduce + bias + relu ----------------
__global__ __launch_bounds__(256) void reduce_bias_relu_k(const float* __restrict__ part,
    const float* __restrict__ bias, float* __restrict__ outp, int Ndim, int S, int MN)
{
    int m = blockIdx.x, t = threadIdx.x;
    size_t o = (size_t)m * Ndim + t * 4;
    float4 acc = *(const float4*)&part[o];
    for (int s = 1; s < S; ++s) {
        float4 p = *(const float4*)&part[(size_t)s * MN + o];
        acc.x += p.x; acc.y += p.y; acc.z += p.z; acc.w += p.w;
    }
    float4 bv = *(const float4*)&bias[t * 4];
    acc.x = fmaxf(acc.x + bv.x, 0.f);
    acc.y = fmaxf(acc.y + bv.y, 0.f);
    acc.z = fmaxf(acc.z + bv.z, 0.f);
    acc.w = fmaxf(acc.w + bv.w, 0.f);
    *(float4*)&outp[o] = acc;
}

// ---------------- cls/box heads ----------------
__global__ __launch_bounds__(128) void heads_k(const float* __restrict__ h,
    const float* __restrict__ w_cls, const float* __restrict__ b_cls,
    const float* __restrict__ w_box, const float* __restrict__ b_box,
    float* __restrict__ logits, float* __restrict__ deltas)
{
    __shared__ float sh[1024];
    int n = blockIdx.x;
    for (int i = threadIdx.x; i < 1024; i += 128) sh[i] = h[(size_t)n * 1024 + i];
    __syncthreads();
    int j = threadIdx.x;
    if (j < 21) {
        float acc = b_cls[j];
        for (int k = 0; k < 1024; ++k) acc += sh[k] * w_cls[k * 21 + j];
        logits[n * 21 + j] = acc;
    } else if (j < 105) {
        int jj = j - 21;
        float acc = b_box[jj];
        for (int k = 0; k < 1024; ++k) acc += sh[k] * w_box[k * 84 + jj];
        deltas[n * 84 + jj] = acc;
    }
}

// ---------------- softmax + decode + clip + mask ----------------
__global__ __launch_bounds__(64) void postproc_k(const float* __restrict__ logits,
    const float* __restrict__ deltas, const float* __restrict__ prop,
    const int* __restrict__ img_h_p, const int* __restrict__ img_w_p,
    float* __restrict__ scores_m, float* __restrict__ boxes_dec)
{
    int n = blockIdx.x;
    int cls = threadIdx.x;
    if (cls < 1 || cls > 20) return;
    float mx = -3.0e38f;
    for (int i = 0; i < 21; ++i) mx = fmaxf(mx, logits[n * 21 + i]);
    float sum = 0.f;
    for (int i = 0; i < 21; ++i) sum += expf(logits[n * 21 + i] - mx);
    float score = expf(logits[n * 21 + cls] - mx) / sum;

    float p0 = prop[n * 4 + 0], p1 = prop[n * 4 + 1];
    float p2 = prop[n * 4 + 2], p3 = prop[n * 4 + 3];
    float w = p2 - p0, h = p3 - p1;
    float cx = p0 + 0.5f * w, cy = p1 + 0.5f * h;
    float d0 = deltas[n * 84 + cls * 4 + 0];
    float d1 = deltas[n * 84 + cls * 4 + 1];
    float d2 = deltas[n * 84 + cls * 4 + 2];
    float d3 = deltas[n * 84 + cls * 4 + 3];
    const float CLIP = 4.135166556742356f;  // log(1000/16)
    float dx = d0 / 10.0f, dy = d1 / 10.0f;
    float dw = fminf(d2 / 5.0f, CLIP), dh = fminf(d3 / 5.0f, CLIP);
    float pcx = dx * w + cx, pcy = dy * h + cy;
    float pw = expf(dw) * w, ph = expf(dh) * h;
    float bx1 = pcx - 0.5f * pw, by1 = pcy - 0.5f * ph;
    float bx2 = pcx + 0.5f * pw, by2 = pcy + 0.5f * ph;
    float iw = (float)img_w_p[0], ih = (float)img_h_p[0];
    bx1 = fminf(fmaxf(bx1, 0.f), iw);
    by1 = fminf(fmaxf(by1, 0.f), ih);
    bx2 = fminf(fmaxf(bx2, 0.f), iw);
    by2 = fminf(fmaxf(by2, 0.f), ih);
    float bw = bx2 - bx1, bh = by2 - by1;
    bool keep = (bw >= 1.0f) && (bh >= 1.0f) && (score >= 0.05f);
    int o = (cls - 1) * 1000 + n;
    scores_m[o] = keep ? score : NEGV;
    ((float4*)boxes_dec)[o] = make_float4(bx1, by1, bx2, by2);
}

// ---------------- per-class NMS ----------------
// grid = 20 blocks (one/class), 1024 thr. Exact JAX scan semantics.
__global__ __launch_bounds__(1024) void nms_k(const float* __restrict__ scores_m,
    const float* __restrict__ boxes_dec, float* __restrict__ out)
{
    int cls = blockIdx.x;
    int t = threadIdx.x;
    __shared__ float s[1000];
    __shared__ float4 bx[1000];
    __shared__ unsigned long long red[16];
    __shared__ float4 selb_s;
    __shared__ int seli_s;
    __shared__ int done_s;
    if (t < 1000) {
        s[t] = scores_m[cls * 1000 + t];
        bx[t] = ((const float4*)boxes_dec)[cls * 1000 + t];
    }
    float* kb  = out;            // [2000][4]
    float* ksc = out + 8000;     // [2000]
    float* klab = out + 10000;   // [2000]
    if (t < 100) klab[cls * 100 + t] = (float)(cls + 1);
    if (t == 0) done_s = 0;
    __syncthreads();
    for (int it = 0; it < 100; ++it) {
        float v = (t < 1000) ? s[t] : -3.0e38f;
        unsigned ub = __float_as_uint(v);
        ub = (ub & 0x80000000u) ? ~ub : (ub | 0x80000000u);
        unsigned long long key = ((unsigned long long)ub << 32) | (unsigned)(1023 - t);
#pragma unroll
        for (int off = 1; off < 64; off <<= 1) {
            unsigned long long o = __shfl_xor(key, off, 64);
            key = (o > key) ? o : key;
        }
        if ((t & 63) == 0) red[t >> 6] = key;
        __syncthreads();
        if (t == 0) {
            unsigned long long best = red[0];
            for (int i = 1; i < 16; ++i) if (red[i] > best) best = red[i];
            int idx = 1023 - (int)(best & 0xFFFFFFFFu);
            float bv = s[idx];
            seli_s = idx;
            selb_s = bx[idx];
            if (bv <= 0.5f * NEGV) {
                done_s = 1;
            } else {
                ((float4*)kb)[cls * 100 + it] = bx[idx];
                ksc[cls * 100 + it] = bv;
            }
        }
        __syncthreads();
        if (done_s) {
            for (int k = it + t; k < 100; k += 1024) {
                ((float4*)kb)[cls * 100 + k] = make_float4(0.f, 0.f, 0.f, 0.f);
                ksc[cls * 100 + k] = 0.0f;
            }
            break;
        }
        if (t < 1000) {
            float4 b = selb_s;
            float4 c = bx[t];
            float ltx = fmaxf(b.x, c.x), lty = fmaxf(b.y, c.y);
            float rbx = fminf(b.z, c.z), rby = fminf(b.w, c.w);
            float wiw = fmaxf(rbx - ltx, 0.0f), wih = fmaxf(rby - lty, 0.0f);
            float inter = wiw * wih;
            float a1 = (b.z - b.x) * (b.w - b.y);
            float a2 = (c.z - c.x) * (c.w - c.y);
            float iou = inter / (a1 + a2 - inter + 1e-9f);
            if (iou > 0.5f || t == seli_s) s[t] = NEGV;
        }
        __syncthreads();
    }
}

extern "C" void kernel_launch(void* const* d_in, const int* in_sizes, int n_in,
                              void* d_out, int out_size, void* d_ws, size_t ws_size,
                              hipStream_t stream)
{
    const float* feat  = (const float*)d_in[0];
    const float* prop  = (const float*)d_in[1];
    const float* w1    = (const float*)d_in[2];
    const float* b1    = (const float*)d_in[3];
    const float* w2    = (const float*)d_in[4];
    const float* b2    = (const float*)d_in[5];
    const float* w_cls = (const float*)d_in[6];
    const float* b_cls = (const float*)d_in[7];
    const float* w_box = (const float*)d_in[8];
    const float* b_box = (const float*)d_in[9];
    const int* img_h   = (const int*)d_in[10];
    const int* img_w   = (const int*)d_in[11];

    float* ws = (float*)d_ws;
    float* pooled    = ws;                       // 1000*12544 (p-major K)
    float* h1        = pooled + 12544000;        // 1000*1024
    float* h2        = h1 + 1024000;             // 1000*1024
    float* part      = h2 + 1024000;             // 4*1000*1024
    float* logits    = part + 4096000;           // 1000*21
    float* deltas    = logits + 21000;           // 1000*84
    float* scores_m  = deltas + 84000;           // 20*1000
    float* boxes_dec = scores_m + 20000;         // 20*1000*4
    float* outp = (float*)d_out;                 // kb 8000 | ksc 2000 | labels 2000

    hipLaunchKernelGGL(roi_align_k, dim3(49, 1000), dim3(256), 0, stream, feat, prop, pooled);
    hipLaunchKernelGGL(gemm_splitk, dim3(8, 16, 4), dim3(256), 0, stream,
                       pooled, w1, part, 1000, 1024, 12544, 3136, 1);
    hipLaunchKernelGGL(reduce_bias_relu_k, dim3(1000), dim3(256), 0, stream,
                       part, b1, h1, 1024, 4, 1024000);
    hipLaunchKernelGGL(gemm_splitk, dim3(8, 16, 4), dim3(256), 0, stream,
                       h1, w2, part, 1000, 1024, 1024, 256, 0);
    hipLaunchKernelGGL(reduce_bias_relu_k, dim3(1000), dim3(256), 0, stream,
                       part, b2, h2, 1024, 4, 1024000);
    hipLaunchKernelGGL(heads_k, dim3(1000), dim3(128), 0, stream,
                       h2, w_cls, b_cls, w_box, b_box, logits, deltas);
    hipLaunchKernelGGL(postproc_k, dim3(1000), dim3(64), 0, stream,
                       logits, deltas, prop, img_h, img_w, scores_m, boxes_dec);
    hipLaunchKernelGGL(nms_k, dim3(20), dim3(1024), 0, stream, scores_m, boxes_dec, outp);
}